// Round 5
// baseline (255.703 us; speedup 1.0000x reference)
//
#include <hip/hip_runtime.h>
#include <stdint.h>

typedef unsigned long long u64;

// Binarized MLP: every matmul is sign(x) @ sign(w)^T => XOR+popcount on
// bit-packed rows: dot = K - 2*popcount(xa ^ xw).
// Round 5: ALL MAC operands from LDS. Weights pre-packed into 8 chunks of
// 1088 u128 (pair-interleaved: u128 = {word 2p, word 2p+1} of one column),
// streamed through a 2x17KB LDS double buffer (load next chunk -> regs,
// MAC current from LDS, ds_write next, barrier). Block = 1024 thr (16
// waves), 4 rows/wave, grid 256 = 1 block/CU => 4 waves/SIMD. Acts are
// wave-private in LDS (no inter-layer barriers); L1 padded to 16 k-words
// (pads 0 on both operands) so there is no tail path.

#define NB    16384
#define DIN   784
#define HID   512
#define DOUT  10
#define CH128 1088            // u128 per chunk (1024 weights + 64 pad/W4)
#define CH64  2176            // u64 per chunk

// ---------------- weight pack: chunked, pair-interleaved ----------------
// W1 (chunks 0-3): col c, word k (0..15; e>=784 pads to 0):
//   p=k>>1; Wg[(p>>1)*2176 + ((p&1)*512 + c)*2 + (k&1)]
// W2 (chunks 4-5), W3 (chunks 6-7): same with k 0..7.
// W4: Wg[7*2176 + 2048 + k*16 + col]  (transposed: lane-stride 1 in fused L4)
__global__ void bmlp_pack_w(const float* __restrict__ w1, const float* __restrict__ w2,
                            const float* __restrict__ w3, const float* __restrict__ w4,
                            u64* __restrict__ Wg)
{
    int gw   = (int)((blockIdx.x * blockDim.x + threadIdx.x) >> 6);
    int lane = threadIdx.x & 63;

    if (gw < 8192) {                        // W1: 512 cols x 16 words
        int c = gw >> 4, k = gw & 15;
        int e = k * 64 + lane;
        float v = (e < DIN) ? w1[c * DIN + e] : 1.0f;   // pad -> bit 0
        u64 word = __ballot(v < 0.0f);
        int p = k >> 1;
        int idx = (p >> 1) * CH64 + ((p & 1) * 512 + c) * 2 + (k & 1);
        if (lane == 0) Wg[idx] = word;
        return;
    }
    gw -= 8192;
    if (gw < 4096) {                        // W2: 512 cols x 8 words
        int c = gw >> 3, k = gw & 7;
        u64 word = __ballot(w2[c * HID + k * 64 + lane] < 0.0f);
        int p = k >> 1;
        int idx = (4 + (p >> 1)) * CH64 + ((p & 1) * 512 + c) * 2 + (k & 1);
        if (lane == 0) Wg[idx] = word;
        return;
    }
    gw -= 4096;
    if (gw < 4096) {                        // W3
        int c = gw >> 3, k = gw & 7;
        u64 word = __ballot(w3[c * HID + k * 64 + lane] < 0.0f);
        int p = k >> 1;
        int idx = (6 + (p >> 1)) * CH64 + ((p & 1) * 512 + c) * 2 + (k & 1);
        if (lane == 0) Wg[idx] = word;
        return;
    }
    gw -= 4096;
    if (gw < 80) {                          // W4: 10 cols x 8 words
        int jj = gw >> 3, k = gw & 7;
        u64 word = __ballot(w4[jj * HID + k * 64 + lane] < 0.0f);
        int idx = 7 * CH64 + 2048 + k * 16 + jj;
        if (lane == 0) Wg[idx] = word;
    }
}

// -------------------------- fused MLP --------------------------
// 2 k-pairs of MACs from an LDS chunk buffer. Weight reads: contiguous
// b128 (64 lanes x 16B = 1KB, conflict-free). Act reads: wave-broadcast.
template<int PAIR_OFF, int ASTR>
__device__ __forceinline__ void mac2(const ulonglong2* Wb, const u64* A,
                                     int cnt[8][4], int lane)
{
#pragma unroll
    for (int p = 0; p < 2; ++p) {
        ulonglong2 wv[8];
#pragma unroll
        for (int cb = 0; cb < 8; ++cb)
            wv[cb] = Wb[p * 512 + cb * 64 + lane];
#pragma unroll
        for (int r = 0; r < 4; ++r) {
            ulonglong2 a = *reinterpret_cast<const ulonglong2*>(A + r * ASTR + 2 * (PAIR_OFF + p));
#pragma unroll
            for (int cb = 0; cb < 8; ++cb) {
                cnt[cb][r] += (int)__popcll(a.x ^ wv[cb].x);
                cnt[cb][r] += (int)__popcll(a.y ^ wv[cb].y);
            }
        }
    }
}

// BN + hardtanh sign epilogue, exact reference op order (proven r1-r4):
// A = g*(1/sqrt(v+eps)); y = ((dot+b)-m)*A + be; sign -> ballot.
// Lane L = r*8+cb keeps word (r,cb); lanes<32 write the wave's 32 out-words.
__device__ __forceinline__ void epi(int cnt[8][4], u64* dst,
    const float* __restrict__ b, const float* __restrict__ g,
    const float* __restrict__ be, const float* __restrict__ m,
    const float* __restrict__ v, float eps, int K, int lane)
{
    float pb[8], pm[8], pe[8], pA[8];
#pragma unroll
    for (int cb = 0; cb < 8; ++cb) {
        int c = cb * 64 + lane;
        pb[cb] = b[c]; pm[cb] = m[c]; pe[cb] = be[c];
        pA[cb] = __fmul_rn(g[c], __fdiv_rn(1.0f, __fsqrt_rn(__fadd_rn(v[c], eps))));
    }
    u64 myw = 0;
#pragma unroll
    for (int r = 0; r < 4; ++r) {
#pragma unroll
        for (int cb = 0; cb < 8; ++cb) {
            float dotf = (float)(K - 2 * cnt[cb][r]);       // exact integer
            float xl = __fadd_rn(dotf, pb[cb]);
            float y  = __fadd_rn(__fmul_rn(__fsub_rn(xl, pm[cb]), pA[cb]), pe[cb]);
            u64 bal = __ballot(y < 0.0f);                   // bit=1 <=> -1
            myw = (lane == r * 8 + cb) ? bal : myw;
        }
    }
    if (lane < 32) dst[lane] = myw;
}

struct Stg { ulonglong2 t0, t1; };
__device__ __forceinline__ Stg stage_load(const ulonglong2* __restrict__ src, int tid)
{
    Stg s;
    s.t0 = src[tid];
    if (tid < 64) s.t1 = src[1024 + tid];   // wave-uniform guard (wave 0)
    return s;
}
__device__ __forceinline__ void stage_write(ulonglong2* dst, const Stg& s, int tid)
{
    dst[tid] = s.t0;
    if (tid < 64) dst[1024 + tid] = s.t1;
}

#define RESET_CNT() do {                                   \
    _Pragma("unroll") for (int cb = 0; cb < 8; ++cb)       \
    _Pragma("unroll") for (int r = 0; r < 4; ++r)          \
        cnt[cb][r] = 0; } while (0)

__global__ __launch_bounds__(1024, 4)
void bmlp_fused(const float* __restrict__ x, const u64* __restrict__ Wg,
                const float* __restrict__ b1, const float* __restrict__ g1,
                const float* __restrict__ be1, const float* __restrict__ m1,
                const float* __restrict__ v1,
                const float* __restrict__ b2, const float* __restrict__ g2,
                const float* __restrict__ be2, const float* __restrict__ m2,
                const float* __restrict__ v2,
                const float* __restrict__ b3, const float* __restrict__ g3,
                const float* __restrict__ be3, const float* __restrict__ m3,
                const float* __restrict__ v3,
                const float* __restrict__ b4,
                float* __restrict__ out)
{
    // LDS: 2 weight chunk buffers (2x2176 u64) + 16 waves x 128 u64 acts
    __shared__ __align__(16) u64 smem[2 * CH64 + 16 * 128];   // 51200 B
    const int tid = threadIdx.x, w = tid >> 6, lane = tid & 63;
    u64* Aw = smem + 2 * CH64 + w * 128;    // wave acts: A1[4][16] | A2[4][8] | A3[4][8]
    ulonglong2* buf0 = reinterpret_cast<ulonglong2*>(smem);
    ulonglong2* buf1 = reinterpret_cast<ulonglong2*>(smem + CH64);
    const ulonglong2* Wg2 = reinterpret_cast<const ulonglong2*>(Wg);
    const int row0 = blockIdx.x * 64 + w * 4;

    // chunk 0 -> buf0 (direct copy)
    { Stg s = stage_load(Wg2, tid); stage_write(buf0, s, tid); }

    // pack my 4 x-rows into A1 (wave-private; ballot -> lane0 write)
#pragma unroll 2
    for (int r = 0; r < 4; ++r) {
        const float* xr = x + (size_t)(row0 + r) * DIN;
#pragma unroll
        for (int k = 0; k < 13; ++k) {
            int e = k * 64 + lane;
            float vx = (e < DIN) ? xr[e] : 1.0f;            // pad -> bit 0
            u64 word = __ballot(vx < 0.0f);
            if (lane == 0) Aw[r * 16 + k] = word;
        }
    }
    if (lane < 16 && (lane & 3)) Aw[(lane >> 2) * 16 + 12 + (lane & 3)] = 0; // words 13-15
    __syncthreads();                                        // chunk0 + acts ready

    int cnt[8][4];
    RESET_CNT();

    // ---- L1: chunks 0-3 (pairs 0..7, acts A1 stride 16) ----
    { Stg s = stage_load(Wg2 + 1 * CH128, tid);
      mac2<0, 16>(buf0, Aw, cnt, lane);
      stage_write(buf1, s, tid); }
    __syncthreads();
    { Stg s = stage_load(Wg2 + 2 * CH128, tid);
      mac2<2, 16>(buf1, Aw, cnt, lane);
      stage_write(buf0, s, tid); }
    __syncthreads();
    { Stg s = stage_load(Wg2 + 3 * CH128, tid);
      mac2<4, 16>(buf0, Aw, cnt, lane);
      stage_write(buf1, s, tid); }
    __syncthreads();
    { Stg s = stage_load(Wg2 + 4 * CH128, tid);
      mac2<6, 16>(buf1, Aw, cnt, lane);
      epi(cnt, Aw + 64, b1, g1, be1, m1, v1, 1e-5f, DIN, lane);
      stage_write(buf0, s, tid); }
    __syncthreads();

    // ---- L2: chunks 4-5 (acts A2 = Aw+64, stride 8) ----
    RESET_CNT();
    { Stg s = stage_load(Wg2 + 5 * CH128, tid);
      mac2<0, 8>(buf0, Aw + 64, cnt, lane);
      stage_write(buf1, s, tid); }
    __syncthreads();
    { Stg s = stage_load(Wg2 + 6 * CH128, tid);
      mac2<2, 8>(buf1, Aw + 64, cnt, lane);
      epi(cnt, Aw + 96, b2, g2, be2, m2, v2, 1e-5f, HID, lane);
      stage_write(buf0, s, tid); }
    __syncthreads();

    // ---- L3: chunks 6-7 (acts A3 = Aw+96); eps=512 source bug ----
    RESET_CNT();
    { Stg s = stage_load(Wg2 + 7 * CH128, tid);
      mac2<0, 8>(buf0, Aw + 96, cnt, lane);
      stage_write(buf1, s, tid); }
    __syncthreads();
    { mac2<2, 8>(buf1, Aw + 96, cnt, lane);
      epi(cnt, Aw + 64, b3, g3, be3, m3, v3, 512.0f, HID, lane); }  // -> A2 region

    // ---- L4: out = dot + b4 (W4 lives in chunk 7 = buf1, transposed) ----
    {
        const u64* W4l = reinterpret_cast<const u64*>(buf1);
        int r = lane >> 4, cc = lane & 15;
        if (cc < DOUT) {
            const u64* arow = Aw + 64 + r * 8;
            int mm = 0;
#pragma unroll
            for (int k = 0; k < 8; ++k)
                mm += (int)__popcll(arow[k] ^ W4l[2048 + k * 16 + cc]);
            out[(size_t)(row0 + r) * DOUT + cc] =
                __fadd_rn((float)(HID - 2 * mm), b4[cc]);
        }
    }
}

extern "C" void kernel_launch(void* const* d_in, const int* in_sizes, int n_in,
                              void* d_out, int out_size, void* d_ws, size_t ws_size,
                              hipStream_t stream)
{
    const float* x   = (const float*)d_in[0];
    const float* w1  = (const float*)d_in[1];
    const float* b1  = (const float*)d_in[2];
    const float* g1  = (const float*)d_in[3];
    const float* be1 = (const float*)d_in[4];
    const float* m1  = (const float*)d_in[5];
    const float* v1  = (const float*)d_in[6];
    const float* w2  = (const float*)d_in[7];
    const float* b2  = (const float*)d_in[8];
    const float* g2  = (const float*)d_in[9];
    const float* be2 = (const float*)d_in[10];
    const float* m2  = (const float*)d_in[11];
    const float* v2  = (const float*)d_in[12];
    const float* w3  = (const float*)d_in[13];
    const float* b3  = (const float*)d_in[14];
    const float* g3  = (const float*)d_in[15];
    const float* be3 = (const float*)d_in[16];
    const float* m3  = (const float*)d_in[17];
    const float* v3  = (const float*)d_in[18];
    const float* w4  = (const float*)d_in[19];
    const float* b4  = (const float*)d_in[20];
    float* out = (float*)d_out;

    u64* Wg = (u64*)d_ws;                   // 8 chunks x 2176 u64 = 139264 B

    // pack: 8192 + 4096 + 4096 + 80 = 16464 waves -> 4116 blocks of 256
    bmlp_pack_w<<<dim3(4116), 256, 0, stream>>>(w1, w2, w3, w4, Wg);

    // fused: 256 blocks x 1024 thr (16 waves x 4 rows = 64 rows/block)
    bmlp_fused<<<dim3(NB / 64), 1024, 0, stream>>>(
        x, Wg,
        b1, g1, be1, m1, v1,
        b2, g2, be2, m2, v2,
        b3, g3, be3, m3, v3,
        b4, out);
}

// Round 6
// 68.494 us; speedup vs baseline: 3.7332x; 3.7332x over previous
//
#include <hip/hip_runtime.h>
#include <stdint.h>

typedef unsigned long long u64;

// Binarized MLP: every matmul is sign(x) @ sign(w)^T => XOR+popcount on
// bit-packed rows: dot = K - 2*popcount(xa ^ xw).
// Round 6: round-1 geometry (512 thr/block, 32 rows/block, 512 blocks =
// 16 waves/CU = 4/SIMD), 1 col/thread (26 weight VGPRs), acts wave-broadcast
// from LDS, weights PINNED in registers via opaque asm (round 1/3 disease:
// compiler remat'd weight loads into the row loop -> per-row L2 reloads).
// NO min-occupancy launch_bounds (round 5 disease: forced VGPR=64 -> 0.76 GB
// scratch spill traffic).

#define NB   16384
#define DIN  784
#define HID  512
#define DOUT 10
#define KW1  13      // ceil(784/64)
#define KW2  8       // 512/64
#define RB   32      // rows per block
#define AST1 14      // L1 act row stride (u64): r*14+2k stays 16B-aligned

// ---------------- combined weight pack (one dispatch; proven r3/r4) -------
// w1/w2/w3 transposed-packed WT[k*HID + col]; w4 row-packed W4p[c*8+k].
// Pad bits (784 tail) = 0 on both operands -> never mismatch.
__global__ void bmlp_pack_w(const float* __restrict__ w1, const float* __restrict__ w2,
                            const float* __restrict__ w3, const float* __restrict__ w4,
                            u64* __restrict__ W1T, u64* __restrict__ W2T,
                            u64* __restrict__ W3T, u64* __restrict__ W4p)
{
    int gw   = (int)((blockIdx.x * blockDim.x + threadIdx.x) >> 6);
    int lane = threadIdx.x & 63;

    if (gw < HID * KW1) {                       // w1: [512][784] -> W1T[13][512]
        int r = gw / KW1, k = gw - r * KW1;
        int e = k * 64 + lane;
        float v = (e < DIN) ? w1[r * DIN + e] : 1.0f;   // pad -> bit 0
        u64 word = __ballot(v < 0.0f);
        if (lane == 0) W1T[k * HID + r] = word;
        return;
    }
    gw -= HID * KW1;
    if (gw < HID * KW2) {                       // w2 -> W2T[8][512]
        int r = gw >> 3, k = gw & 7;
        u64 word = __ballot(w2[r * HID + k * 64 + lane] < 0.0f);
        if (lane == 0) W2T[k * HID + r] = word;
        return;
    }
    gw -= HID * KW2;
    if (gw < HID * KW2) {                       // w3
        int r = gw >> 3, k = gw & 7;
        u64 word = __ballot(w3[r * HID + k * 64 + lane] < 0.0f);
        if (lane == 0) W3T[k * HID + r] = word;
        return;
    }
    gw -= HID * KW2;
    if (gw < DOUT * KW2) {                      // w4: [10][512] -> W4p[10][8]
        int r = gw >> 3, k = gw & 7;
        u64 word = __ballot(w4[r * HID + k * 64 + lane] < 0.0f);
        if (lane == 0) W4p[r * KW2 + k] = word;
    }
}

// One binarized layer. Thread = output col j (512 threads = 512 cols).
// Weights held in registers, PINNED against remat. Act rows read as
// wave-broadcast b128 from LDS (same addr across lanes -> ~free).
// BN epilogue exact reference op order (proven r1-r5):
//   A = g*(1/sqrt(v+eps)); y = ((dot+b)-m)*A + be; sign -> ballot word.
template<int KW, int ASTR>
__device__ __forceinline__ void bin_layer(
    const u64* act, u64* actOut, const u64* __restrict__ WT,
    const float* __restrict__ b, const float* __restrict__ g,
    const float* __restrict__ be, const float* __restrict__ m,
    const float* __restrict__ v, float eps, int K)
{
    const int j = threadIdx.x, w = j >> 6, lane = j & 63;

    u64 wr[KW];
#pragma unroll
    for (int k = 0; k < KW; ++k) {
        wr[k] = WT[k * HID + j];                // coalesced 512B/wave
        asm volatile("" : "+v"(wr[k]));         // opaque: cannot remat/reload
    }
    float pb = b[j], pm = m[j], pe = be[j];
    float pA = __fmul_rn(g[j], __fdiv_rn(1.0f, __fsqrt_rn(__fadd_rn(v[j], eps))));
    asm volatile("" : "+v"(pb), "+v"(pm), "+v"(pe), "+v"(pA));

#pragma unroll 4
    for (int r = 0; r < RB; ++r) {
        const u64* row = act + r * ASTR;
        int c0 = 0, c1 = 0;
#pragma unroll
        for (int kp = 0; kp < KW / 2; ++kp) {   // broadcast b128 reads
            ulonglong2 a = *reinterpret_cast<const ulonglong2*>(row + 2 * kp);
            c0 += (int)__popcll(a.x ^ wr[2 * kp]);
            c1 += (int)__popcll(a.y ^ wr[2 * kp + 1]);
        }
        if (KW & 1)                             // L1 tail word 12
            c0 += (int)__popcll(row[KW - 1] ^ wr[KW - 1]);
        float dotf = (float)(K - 2 * (c0 + c1));    // exact integer
        float xl = __fadd_rn(dotf, pb);
        float y  = __fadd_rn(__fmul_rn(__fsub_rn(xl, pm), pA), pe);
        u64 bal = __ballot(y < 0.0f);           // bit=1 <=> -1; word w of row r
        if (lane == 0) actOut[r * KW2 + w] = bal;
    }
}

__global__ __launch_bounds__(512, 2)
void bmlp_fused(const float* __restrict__ x,
                const u64* __restrict__ W1T, const u64* __restrict__ W2T,
                const u64* __restrict__ W3T, const u64* __restrict__ W4p,
                const float* __restrict__ b1, const float* __restrict__ g1,
                const float* __restrict__ be1, const float* __restrict__ m1,
                const float* __restrict__ v1,
                const float* __restrict__ b2, const float* __restrict__ g2,
                const float* __restrict__ be2, const float* __restrict__ m2,
                const float* __restrict__ v2,
                const float* __restrict__ b3, const float* __restrict__ g3,
                const float* __restrict__ be3, const float* __restrict__ m3,
                const float* __restrict__ v3,
                const float* __restrict__ b4,
                float* __restrict__ out)
{
    __shared__ __align__(16) u64 A1[RB * AST1];     // 448 u64
    __shared__ __align__(16) u64 A2[RB * KW2];      // 256
    __shared__ __align__(16) u64 A3[RB * KW2];      // 256  => 7680 B total
    const int t = threadIdx.x, w = t >> 6, lane = t & 63;
    const int row0 = blockIdx.x * RB;

    // pack: wave w packs rows [4w, 4w+4) straight into A1 via ballot
#pragma unroll
    for (int r = 0; r < 4; ++r) {
        const float* xr = x + (size_t)(row0 + w * 4 + r) * DIN;
#pragma unroll
        for (int k = 0; k < KW1; ++k) {
            int e = k * 64 + lane;
            float vx = (e < DIN) ? xr[e] : 1.0f;    // pad -> bit 0
            u64 word = __ballot(vx < 0.0f);
            if (lane == 0) A1[(w * 4 + r) * AST1 + k] = word;
        }
    }
    __syncthreads();

    bin_layer<KW1, AST1>(A1, A2, W1T, b1, g1, be1, m1, v1, 1e-5f, DIN);
    __syncthreads();
    bin_layer<KW2, KW2>(A2, A3, W2T, b2, g2, be2, m2, v2, 1e-5f, HID);
    __syncthreads();
    bin_layer<KW2, KW2>(A3, A2, W3T, b3, g3, be3, m3, v3, 512.0f, HID); // EPS3 bug: 512
    __syncthreads();

    // layer 4: out = dot + b4. 512 threads -> r = t>>4 (32 rows), c = t&15.
    {
        int r = t >> 4, c = t & 15;
        if (c < DOUT) {
            const u64* arow = A2 + r * KW2;
            int mm = 0;
#pragma unroll
            for (int k = 0; k < KW2; ++k)
                mm += (int)__popcll(arow[k] ^ W4p[c * KW2 + k]);
            out[(size_t)(row0 + r) * DOUT + c] =
                __fadd_rn((float)(HID - 2 * mm), b4[c]);
        }
    }
}

extern "C" void kernel_launch(void* const* d_in, const int* in_sizes, int n_in,
                              void* d_out, int out_size, void* d_ws, size_t ws_size,
                              hipStream_t stream)
{
    const float* x   = (const float*)d_in[0];
    const float* w1  = (const float*)d_in[1];
    const float* b1  = (const float*)d_in[2];
    const float* g1  = (const float*)d_in[3];
    const float* be1 = (const float*)d_in[4];
    const float* m1  = (const float*)d_in[5];
    const float* v1  = (const float*)d_in[6];
    const float* w2  = (const float*)d_in[7];
    const float* b2  = (const float*)d_in[8];
    const float* g2  = (const float*)d_in[9];
    const float* be2 = (const float*)d_in[10];
    const float* m2  = (const float*)d_in[11];
    const float* v2  = (const float*)d_in[12];
    const float* w3  = (const float*)d_in[13];
    const float* b3  = (const float*)d_in[14];
    const float* g3  = (const float*)d_in[15];
    const float* be3 = (const float*)d_in[16];
    const float* m3  = (const float*)d_in[17];
    const float* v3  = (const float*)d_in[18];
    const float* w4  = (const float*)d_in[19];
    const float* b4  = (const float*)d_in[20];
    float* out = (float*)d_out;

    // workspace: packed weights only (~119 KB)
    u64* W1T = (u64*)d_ws;
    u64* W2T = W1T + (size_t)KW1 * HID;
    u64* W3T = W2T + (size_t)KW2 * HID;
    u64* W4p = W3T + (size_t)KW2 * HID;

    const int packWaves = HID * KW1 + 2 * HID * KW2 + DOUT * KW2;   // 14928
    bmlp_pack_w<<<dim3((packWaves * 64 + 255) / 256), 256, 0, stream>>>(
        w1, w2, w3, w4, W1T, W2T, W3T, W4p);

    bmlp_fused<<<dim3(NB / RB), 512, 0, stream>>>(
        x, W1T, W2T, W3T, W4p,
        b1, g1, be1, m1, v1,
        b2, g2, be2, m2, v2,
        b3, g3, be3, m3, v3,
        b4, out);
}